// Round 12
// baseline (294.199 us; speedup 1.0000x reference)
//
#include <hip/hip_runtime.h>
#include <math.h>

#pragma clang fp contract(off)

typedef unsigned long long ull;

#define NCLS 80
#define NTOT 3800
#define CAND_CAP 4096
#define NMS_CAP 1024
// score-bits hist over [0.5, 1.0): 1024 bins of 2^13 ULP
#define BIN_LO 0x3F000000u
#define NB 1024
#define BSHIFT 13
#define QPB 1120
#define NBLK 954
#define SEGCAP 512

__constant__ int d_BSQ[6]  = {0, 715, 894, 939, 951, 954};
__constant__ int d_QL[5]   = {800000, 200000, 50000, 12800, 3200};
__constant__ int d_EL[5]   = {3200000, 800000, 200000, 51200, 12800};
__constant__ float d_PREHI[5] = {0.86f, 0.82f, 0.78f, 0.74f, 0.74f};
__constant__ int d_KL[5] = {1000,1000,1000,640,160};
__constant__ int d_OB[5] = {0,1000,2000,3000,3640};

struct Params {
  const float *cls0,*cls1,*cls2,*cls3,*cls4;
  const float *ctn0,*ctn1,*ctn2,*ctn3,*ctn4;
  const float *box0,*box1,*box2,*box3,*box4;
  const int* img;
  ull* pre;                  // NBLK * SEGCAP  (exact-score hit segments)
  unsigned* blkcnt;          // NBLK (plain stores — no init needed)
  unsigned* slot_bits;       // NTOT
  unsigned* slot_label;      // NTOT
  float* slot_box;           // NTOT*4
  float* out;                // 26600 floats
};

__device__ __forceinline__ float fast_sig(float x) {
  return 1.0f / (1.0f + __expf(-x));
}
// exact: emulate ref f32 pipeline with correctly-rounded expf (f64 exp -> f32)
__device__ __forceinline__ float sigmoid_ref(float x) {
  float e = (float)exp(-(double)x);
  return 1.0f / (1.0f + e);
}
__device__ __forceinline__ float score_ref(float c, float t) {
  return sqrtf(sigmoid_ref(c) * sigmoid_ref(t));
}
__device__ __forceinline__ float iou_ref(float ax1,float ay1,float ax2,float ay2,
                                         float bx1,float by1,float bx2,float by2) {
  float areaA = fmaxf(ax2-ax1,0.0f) * fmaxf(ay2-ay1,0.0f);
  float areaB = fmaxf(bx2-bx1,0.0f) * fmaxf(by2-by1,0.0f);
  float ix1 = fmaxf(ax1,bx1), iy1 = fmaxf(ay1,by1);
  float ix2 = fminf(ax2,bx2), iy2 = fminf(ay2,by2);
  float inter = fmaxf(ix2-ix1,0.0f) * fmaxf(iy2-iy1,0.0f);
  float uni = areaA + areaB - inter;
  return inter / fmaxf(uni, 1e-9f);
}
__device__ __forceinline__ const float* cls_of(const Params& p, int l) {
  return (l==0)?p.cls0:(l==1)?p.cls1:(l==2)?p.cls2:(l==3)?p.cls3:p.cls4;
}
__device__ __forceinline__ const float* ctn_of(const Params& p, int l) {
  return (l==0)?p.ctn0:(l==1)?p.ctn1:(l==2)?p.ctn2:(l==3)?p.ctn3:p.ctn4;
}
__device__ __forceinline__ const float* box_of(const Params& p, int l) {
  return (l==0)?p.box0:(l==1)?p.box1:(l==2)?p.box2:(l==3)?p.box3:p.box4;
}

// in-wave threshold search over a 1024-bin LDS hist (redundant per wave,
// identical results). thr = bin-start of largest bin with suffix count >= k.
__device__ __forceinline__ void thr_search(const unsigned* hist, unsigned k,
                                           int lane, unsigned& thr, int& found) {
  int cb = 1008 - 16*lane;            // lane j covers bins [1008-16j, 1024-16j)
  unsigned csum = 0;
  #pragma unroll
  for (int t = 0; t < 16; ++t) csum += hist[cb + t];
  unsigned cum = csum;
  for (int d = 1; d < 64; d <<= 1) {
    unsigned tu = __shfl_up(cum, d);
    if (lane >= d) cum += tu;
  }
  ull okm = __ballot(cum >= k);
  thr = BIN_LO; found = 0;
  if (okm) {
    int j0 = (int)__ffsll((long long)okm) - 1;
    unsigned thrj = BIN_LO;
    if (lane == j0) {
      unsigned acc = cum - csum;
      int cbb = 1008 - 16*j0;
      for (int bb = cbb + 15; bb >= cbb; --bb) {
        acc += hist[bb];
        if (acc >= k) { thrj = BIN_LO + ((unsigned)bb << BSHIFT); break; }
      }
    }
    thr = __shfl(thrj, j0);
    found = 1;
  }
}

// Pass 1: fast scores; hits (fast >= PREHI) exact-rescored in registers and
// written to fixed per-block segments. No global atomics, no init required.
__global__ __launch_bounds__(256) void k_score(Params p) {
  int b = blockIdx.x, tid = threadIdx.x;
  __shared__ ull pbuf[SEGCAP];
  __shared__ unsigned s_cnt;
  if (tid == 0) s_cnt = 0u;
  __syncthreads();
  int l = 0;
  while (b >= d_BSQ[l+1]) ++l;
  int cb = b - d_BSQ[l];
  int q0 = cb * QPB;
  int nq = d_QL[l] - q0; if (nq > QPB) nq = QPB;
  const float* cls = cls_of(p, l);
  const float* ctn = ctn_of(p, l);
  float prehi = d_PREHI[l];
  for (int i = tid; i < nq; i += 256) {
    int q = q0 + i;
    float4 c4 = ((const float4*)cls)[q];
    float ct = ctn[q / 20];               // anchor = (4q)/80
    float st = fast_sig(ct);
    float cv[4] = {c4.x, c4.y, c4.z, c4.w};
    #pragma unroll
    for (int j = 0; j < 4; ++j) {
      float s = sqrtf(fast_sig(cv[j]) * st);
      if (s >= prehi) {
        float ex = score_ref(cv[j], ct);  // exact, operands already in registers
        unsigned pos = atomicAdd(&s_cnt, 1u);
        if (pos < SEGCAP)
          pbuf[pos] = ((ull)__float_as_uint(ex) << 32)
                    | (ull)(0xFFFFFFFFu - (unsigned)(4*q + j));
      }
    }
  }
  __syncthreads();
  unsigned n = s_cnt;
  if (tid == 0) p.blkcnt[b] = n;          // raw; reader clamps + detects overflow
  unsigned nw = n < SEGCAP ? n : SEGCAP;
  ull* seg = p.pre + (size_t)b * SEGCAP;
  for (unsigned i = tid; i < nw; i += 256) seg[i] = pbuf[i];
}

// 80 blocks (16 per level). Streaming is wave-per-segment / lane-per-entry
// (coalesced 64-wide bursts, independent across segments -> high MLP).
// Comparison set key[] built per-block via atomics (order-invariant: keys
// unique). Emission partitioned DETERMINISTICALLY by segment index (fastok) /
// element range (fallback): each selected key emitted by exactly one block.
__global__ __launch_bounds__(256) void k_rank(Params p) {
  int bx = blockIdx.x;
  int l = bx >> 4, t16 = bx & 15;
  int tid = threadIdx.x, lane = tid & 63, wv = tid >> 6;
  __shared__ unsigned hist[NB];
  __shared__ ull key[CAND_CAP];
  __shared__ unsigned short eidx[CAND_CAP];
  __shared__ unsigned bcnt[720];
  __shared__ unsigned s_cnt, e_cnt;
  __shared__ int s_over;
  if (tid == 0) { s_cnt = 0u; e_cnt = 0u; s_over = 0; }
  for (int i = tid; i < NB; i += 256) hist[i] = 0u;
  int s0b = d_BSQ[l], nseg = d_BSQ[l+1] - s0b;
  for (int s = tid; s < nseg; s += 256) {
    unsigned n = p.blkcnt[s0b + s];
    if (n > SEGCAP) { s_over = 1; n = SEGCAP; }
    bcnt[s] = n;
  }
  __syncthreads();
  // hist of exact hit bits: wave-per-segment, lane-per-entry (coalesced)
  for (int s = wv; s < nseg; s += 4) {
    unsigned n = bcnt[s];
    const ull* seg = p.pre + (size_t)(s0b + s) * SEGCAP;
    for (unsigned j0 = 0; j0 < n; j0 += 64) {
      unsigned j = j0 + (unsigned)lane;
      if (j < n) {
        unsigned bits = (unsigned)(seg[j] >> 32);
        unsigned bin = (bits >= BIN_LO) ? ((bits - BIN_LO) >> BSHIFT) : 0u;
        if (bin > NB-1) bin = NB-1;
        atomicAdd(&hist[bin], 1u);
      }
    }
  }
  __syncthreads();
  unsigned k = (unsigned)d_KL[l];
  unsigned thr; int found;
  thr_search(hist, k, lane, thr, found);
  // completeness: exact >= thr must imply hit (fast >= PREHI); |fast-exact|
  // << 1 bin, so require thr >= PREHI + 1 bin.
  bool fastok = (!s_over) && found &&
                (thr >= __float_as_uint(d_PREHI[l]) + (1u << BSHIFT));
  if (fastok) {
    int chunk = (nseg + 15) >> 4;
    int sA = t16 * chunk, sB = sA + chunk;
    if (sA > nseg) sA = nseg;
    if (sB > nseg) sB = nseg;
    for (int s = wv; s < nseg; s += 4) {
      unsigned n = bcnt[s];
      const ull* seg = p.pre + (size_t)(s0b + s) * SEGCAP;
      bool own = (s >= sA) && (s < sB);
      for (unsigned j0 = 0; j0 < n; j0 += 64) {
        unsigned j = j0 + (unsigned)lane;
        if (j < n) {
          ull kk = seg[j];
          if ((unsigned)(kk >> 32) >= thr) {
            unsigned pos = atomicAdd(&s_cnt, 1u);
            if (pos < CAND_CAP) {
              key[pos] = kk;
              if (own) {
                unsigned ep = atomicAdd(&e_cnt, 1u);
                eidx[ep] = (unsigned short)pos;   // ep < CAND_CAP since pos is
              }
            }
          }
        }
      }
    }
  } else {
    // fallback (statistically unreachable): block-local full-level 2-pass
    const float* cls = cls_of(p, l);
    const float* ctn = ctn_of(p, l);
    int ne = d_EL[l];
    __syncthreads();
    for (int i = tid; i < NB; i += 256) hist[i] = 0u;
    __syncthreads();
    for (int e = tid; e < ne; e += 256) {
      float fs = sqrtf(fast_sig(cls[e]) * fast_sig(ctn[e / NCLS]));
      unsigned fb = __float_as_uint(fs);
      if (fb >= BIN_LO) {
        unsigned bin = (fb - BIN_LO) >> BSHIFT;
        if (bin > NB-1) bin = NB-1;
        atomicAdd(&hist[bin], 1u);
      }
    }
    __syncthreads();
    unsigned thr2; int found2;
    thr_search(hist, k, lane, thr2, found2);
    unsigned tf = (found2 && thr2 > BIN_LO) ? (thr2 - (1u << BSHIFT)) : BIN_LO;
    int chunk = (ne + 15) >> 4;
    int eA = t16 * chunk, eB = eA + chunk;
    if (eA > ne) eA = ne;
    if (eB > ne) eB = ne;
    for (int e = tid; e < ne; e += 256) {
      float fs = sqrtf(fast_sig(cls[e]) * fast_sig(ctn[e / NCLS]));
      if (__float_as_uint(fs) >= tf) {
        float ex = score_ref(cls[e], ctn[e / NCLS]);
        unsigned pos = atomicAdd(&s_cnt, 1u);
        if (pos < CAND_CAP) {
          key[pos] = ((ull)__float_as_uint(ex) << 32)
                   | (ull)(0xFFFFFFFFu - (unsigned)e);
          if (e >= eA && e < eB) {
            unsigned ep = atomicAdd(&e_cnt, 1u);
            eidx[ep] = (unsigned short)pos;
          }
        }
      }
    }
  }
  __syncthreads();
  int m = (s_cnt < CAND_CAP) ? (int)s_cnt : CAND_CAP;
  int en = (e_cnt < CAND_CAP) ? (int)e_cnt : CAND_CAP;
  int kL = d_KL[l], obase = d_OB[l];
  float img = (float)(*p.img);
  const float* box = box_of(p, l);
  for (int t = tid; t < en; t += 256) {
    ull mine = key[eidx[t]];
    int rank = 0;
    int mm = m & ~7;
    #pragma unroll 1
    for (int j = 0; j < mm; j += 8) {
      rank += (key[j  ] > mine) + (key[j+1] > mine) + (key[j+2] > mine) + (key[j+3] > mine)
            + (key[j+4] > mine) + (key[j+5] > mine) + (key[j+6] > mine) + (key[j+7] > mine);
    }
    for (int j = mm; j < m; ++j) rank += (key[j] > mine) ? 1 : 0;
    if (rank >= kL) continue;
    int g = obase + rank;
    unsigned bits = (unsigned)(mine >> 32);
    unsigned fi = 0xFFFFFFFFu - (unsigned)(mine & 0xFFFFFFFFu);
    unsigned lab = fi % NCLS;
    unsigned a = fi / NCLS;
    float4 b4 = ((const float4*)box)[a];
    float4 nb;
    nb.x = fminf(fmaxf(b4.x / img, 0.0f), 1.0f);
    nb.y = fminf(fmaxf(b4.y / img, 0.0f), 1.0f);
    nb.z = fminf(fmaxf(b4.z / img, 0.0f), 1.0f);
    nb.w = fminf(fmaxf(b4.w / img, 0.0f), 1.0f);
    p.out[NTOT + g] = (float)lab;
    ((float4*)(p.out + 2*NTOT))[g] = nb;
    ((float4*)p.slot_box)[g] = b4;
    p.slot_bits[g] = bits;
    p.slot_label[g] = lab;
  }
  // defensive fill for [m, kL) (m >= kL in practice; out is poisoned so must write)
  if (t16 == 0) {
    for (int i = tid; i < kL; i += 256) {
      if (i >= m) {
        int g = obase + i;
        p.out[g] = 0.0f;
        p.out[NTOT + g] = 0.0f;
        ((float4*)(p.out + 2*NTOT))[g] = make_float4(0,0,0,0);
        p.out[6*NTOT + g] = 0.0f;
        ((float4*)p.slot_box)[g] = make_float4(0,0,0,0);
        p.slot_bits[g] = 0u;
        p.slot_label[g] = 0xFFFFFFFFu;
      }
    }
  }
}

// Per-class NMS; class lists rebuilt by scanning slot_label (coalesced, cheap).
__global__ __launch_bounds__(64) void k_nms(Params p) {
  int c = blockIdx.x, lane = threadIdx.x;
  __shared__ unsigned mcnt;
  __shared__ ull key[NMS_CAP];
  if (lane == 0) mcnt = 0u;
  __syncthreads();
  for (int g = lane; g < NTOT; g += 64) {
    if (p.slot_label[g] == (unsigned)c) {
      unsigned pos = atomicAdd(&mcnt, 1u);
      if (pos < NMS_CAP)
        key[pos] = ((ull)p.slot_bits[g] << 32) | (ull)(0xFFFFFFFFu - (unsigned)g);
    }
  }
  __syncthreads();
  int m = (mcnt < NMS_CAP) ? (int)mcnt : NMS_CAP;
  if (m == 0) return;
  float off = 2.0f * (float)c;
  if (m <= 64) {
    // single-wave path: shfl/ballot, no quadratic LDS traffic
    ull kk = (lane < m) ? key[lane] : 0ULL;
    int rank = 0;
    #pragma unroll 1
    for (int j = 0; j < 64; ++j) {
      ull kj = __shfl(kk, j);
      rank += (j < m && kj > kk) ? 1 : 0;
    }
    __shared__ ull wkey[64];
    if (lane < m) wkey[rank] = kk;
    __syncthreads();
    ull sk = (lane < m) ? wkey[lane] : 0ULL;
    unsigned g = 0xFFFFFFFFu - (unsigned)(sk & 0xFFFFFFFFu);
    float s = __uint_as_float((unsigned)(sk >> 32));
    float x1=0,y1=0,x2=0,y2=0;
    if (lane < m) {
      float4 b4 = ((const float4*)p.slot_box)[g];
      x1 = b4.x + off; y1 = b4.y + off; x2 = b4.z + off; y2 = b4.w + off;
    }
    ull keepm = __ballot(lane < m && s > 0.05f);
    for (int i = 0; i + 1 < m; ++i) {
      if ((keepm >> i) & 1ULL) {
        float ax1 = __shfl(x1, i), ay1 = __shfl(y1, i);
        float ax2 = __shfl(x2, i), ay2 = __shfl(y2, i);
        bool kept = (keepm >> lane) & 1ULL;
        bool sup = kept && (lane > i) && (lane < m) &&
                   (iou_ref(ax1,ay1,ax2,ay2, x1,y1,x2,y2) > 0.6f);
        keepm &= ~__ballot(sup);
      }
    }
    if (lane < m) {
      int kp = (int)((keepm >> lane) & 1ULL);
      p.out[g] = kp ? s : 0.0f;
      p.out[6*NTOT + g] = kp ? 1.0f : 0.0f;
    }
    return;
  }
  // LDS path (rare: class with >64 members)
  __shared__ ull skey[NMS_CAP];
  __shared__ float bxs[NMS_CAP*4];
  __shared__ int keep[NMS_CAP];
  for (int i = lane; i < m; i += 64) {
    ull mine = key[i];
    int rank = 0;
    for (int j = 0; j < m; ++j) rank += (key[j] > mine) ? 1 : 0;
    skey[rank] = mine;
  }
  __syncthreads();
  for (int j = lane; j < m; j += 64) {
    ull kk = skey[j];
    unsigned g = 0xFFFFFFFFu - (unsigned)(kk & 0xFFFFFFFFu);
    for (int q = 0; q < 4; ++q) bxs[j*4+q] = p.slot_box[g*4+q] + off;
    float s = __uint_as_float((unsigned)(kk >> 32));
    keep[j] = (s > 0.05f) ? 1 : 0;
  }
  __syncthreads();
  for (int i = 0; i + 1 < m; ++i) {
    if (keep[i]) {
      float ax1 = bxs[i*4+0], ay1 = bxs[i*4+1], ax2 = bxs[i*4+2], ay2 = bxs[i*4+3];
      for (int j = i + 1 + lane; j < m; j += 64) {
        if (keep[j]) {
          if (iou_ref(ax1,ay1,ax2,ay2, bxs[j*4+0],bxs[j*4+1],bxs[j*4+2],bxs[j*4+3]) > 0.6f)
            keep[j] = 0;
        }
      }
    }
    __syncthreads();
  }
  for (int j = lane; j < m; j += 64) {
    ull kk = skey[j];
    unsigned g = 0xFFFFFFFFu - (unsigned)(kk & 0xFFFFFFFFu);
    float s = __uint_as_float((unsigned)(kk >> 32));
    int kp = keep[j];
    p.out[g] = kp ? s : 0.0f;
    p.out[6*NTOT + g] = kp ? 1.0f : 0.0f;
  }
}

extern "C" void kernel_launch(void* const* d_in, const int* in_sizes, int n_in,
                              void* d_out, int out_size, void* d_ws, size_t ws_size,
                              hipStream_t stream) {
  Params p;
  p.cls0 = (const float*)d_in[0];  p.ctn0 = (const float*)d_in[1];  p.box0 = (const float*)d_in[2];
  p.cls1 = (const float*)d_in[3];  p.ctn1 = (const float*)d_in[4];  p.box1 = (const float*)d_in[5];
  p.cls2 = (const float*)d_in[6];  p.ctn2 = (const float*)d_in[7];  p.box2 = (const float*)d_in[8];
  p.cls3 = (const float*)d_in[9];  p.ctn3 = (const float*)d_in[10]; p.box3 = (const float*)d_in[11];
  p.cls4 = (const float*)d_in[12]; p.ctn4 = (const float*)d_in[13]; p.box4 = (const float*)d_in[14];
  p.img  = (const int*)d_in[15];

  char* w = (char*)d_ws;
  p.pre = (ull*)w;             w += (size_t)NBLK*SEGCAP*8;   // 3,907,584
  p.blkcnt = (unsigned*)w;     w += (size_t)NBLK*4 + 64;     // 3,880
  p.slot_bits  = (unsigned*)w; w += NTOT*4;
  p.slot_label = (unsigned*)w; w += NTOT*4;
  p.slot_box   = (float*)w;    w += NTOT*16;
  p.out = (float*)d_out;

  hipLaunchKernelGGL(k_score, dim3(NBLK), dim3(256), 0, stream, p);
  hipLaunchKernelGGL(k_rank,  dim3(80),   dim3(256), 0, stream, p);
  hipLaunchKernelGGL(k_nms,   dim3(80),   dim3(64),  0, stream, p);
}